// Round 1
// baseline (135.974 us; speedup 1.0000x reference)
//
#include <hip/hip_runtime.h>
#include <hip/hip_bf16.h>

// MultiHeadLinearAttention2D on MI355X (gfx950), bf16-MFMA implementation.
// B=16, C_in=C_out=256, H=W=64 (M=4096), heads=8, dh=32, scale=1/sqrt(32).

typedef __attribute__((ext_vector_type(8))) short bf16x8;
typedef __attribute__((ext_vector_type(4))) float f32x4;
typedef __attribute__((ext_vector_type(4))) unsigned int u32x4;
typedef __attribute__((ext_vector_type(4))) float float4v;

#define DEVI static __device__ __forceinline__

DEVI unsigned short f2bf(float f){
  unsigned int u = __builtin_bit_cast(unsigned int, f);
  u = (u + 0x7fffu + ((u >> 16) & 1u)) >> 16;   // RNE truncate to bf16
  return (unsigned short)u;
}

DEVI f32x4 mfma16(u32x4 a, u32x4 b, f32x4 c){
  return __builtin_amdgcn_mfma_f32_16x16x32_bf16(
      __builtin_bit_cast(bf16x8, a), __builtin_bit_cast(bf16x8, b), c, 0, 0, 0);
}

// byte-XOR swizzles (G4): keep 16B-slot permutation keyed on the row index
DEVI int swz8(int m){ return ((m ^ (m >> 3)) & 7) << 4; }  // for 512B rows
DEVI int swz4(int r){ return ((r ^ (r >> 2)) & 3) << 4; }  // for 64B rows

// Stage fp32 x-tile [256 c][64 m] (c-major global) into LDS bf16 transposed
// x^T [m][256 c], swizzled. Each thread: 4x dwordx4 loads (coalesced along m),
// repack 4x4, 4x 8B LDS writes.
DEVI void stage_x(const float* __restrict__ xb, int m0, unsigned short* xT, int tid){
  #pragma unroll
  for (int it = 0; it < 2; ++it){
    int cq = (tid >> 4) + it * 32;     // 0..63  -> c0 = 4*cq
    int mq = tid & 15;                 // 0..15  -> ml0 = 4*mq
    int c0 = cq * 4, ml0 = mq * 4;
    const float* p = xb + (size_t)c0 * 4096 + m0 + ml0;
    float4v r0 = *(const float4v*)(p);
    float4v r1 = *(const float4v*)(p + 4096);
    float4v r2 = *(const float4v*)(p + 8192);
    float4v r3 = *(const float4v*)(p + 12288);
    #pragma unroll
    for (int j = 0; j < 4; ++j){
      int m = ml0 + j;
      unsigned int lo = (unsigned int)f2bf(r0[j]) | ((unsigned int)f2bf(r1[j]) << 16);
      unsigned int hi = (unsigned int)f2bf(r2[j]) | ((unsigned int)f2bf(r3[j]) << 16);
      int off = m * 512 + ((c0 * 2) ^ swz8(m));
      unsigned long long v = (unsigned long long)lo | ((unsigned long long)hi << 32);
      *(unsigned long long*)((char*)xT + off) = v;
    }
  }
}

// ---------------- kernel 0: weight fp32 -> bf16 ----------------
__global__ void wconv(const float* __restrict__ wq, const float* __restrict__ wk,
                      const float* __restrict__ wv,
                      unsigned short* __restrict__ wkv, unsigned short* __restrict__ wqb){
  int i = blockIdx.x * 256 + threadIdx.x;
  if (i < 65536){
    wkv[i]         = f2bf(wk[i]);   // rows 0..255   = Wk
    wkv[65536 + i] = f2bf(wv[i]);   // rows 256..511 = Wv
    wqb[i]         = f2bf(wq[i]);
  }
}

// ---------------- kernel 1: K/V projection + per-chunk KV & ksum partials ----
// grid (16 chunks, 16 batches), 512 threads = 8 waves = 8 heads.
__global__ void __launch_bounds__(512) k_kv(const float* __restrict__ x,
        const unsigned short* __restrict__ wkv,
        float* __restrict__ kvp, float* __restrict__ ksp){
  __shared__ unsigned short xT[16384];      // 32KB: x^T [64 m][256 c] bf16, swizzled
  __shared__ unsigned short kvw[8][2048];   // 32KB: per-wave [64 rows][32 m] bf16
  const int tid = threadIdx.x, lane = tid & 63, w = tid >> 6;
  const int l15 = lane & 15, hi = lane >> 4;
  const int ch = blockIdx.x, b = blockIdx.y;
  const float* xb = x + (size_t)b * (256 * 4096);

  f32x4 kvacc[2][2];
  f32x4 ksacc[2];
  #pragma unroll
  for (int i = 0; i < 2; ++i){
    ksacc[i] = f32x4{0.f,0.f,0.f,0.f};
    #pragma unroll
    for (int j = 0; j < 2; ++j) kvacc[i][j] = f32x4{0.f,0.f,0.f,0.f};
  }
  u32x4 ones = {0u,0u,0u,0u};               // B-frag: column d=0 all-ones -> ksum
  if (l15 == 0){ ones[0] = ones[1] = ones[2] = ones[3] = 0x3f803f80u; }

  for (int sub = 0; sub < 4; ++sub){
    int m0 = ch * 256 + sub * 64;
    __syncthreads();                         // previous tile fully consumed
    stage_x(xb, m0, xT, tid);
    __syncthreads();

    f32x4 acc[4][4];                         // [o-tile][n-tile]; ot 0,1=K rows, 2,3=V rows
    #pragma unroll
    for (int a1 = 0; a1 < 4; ++a1)
      #pragma unroll
      for (int a2 = 0; a2 < 4; ++a2) acc[a1][a2] = f32x4{0.f,0.f,0.f,0.f};

    for (int kk = 0; kk < 8; ++kk){
      u32x4 bfg[4];
      #pragma unroll
      for (int nt = 0; nt < 4; ++nt){
        int m = nt * 16 + l15;
        bfg[nt] = *(const u32x4*)((const char*)xT + m * 512 + ((kk * 64 + hi * 16) ^ swz8(m)));
      }
      #pragma unroll
      for (int ot = 0; ot < 4; ++ot){
        int row = (ot < 2) ? (w * 32 + ot * 16 + l15)
                           : (256 + w * 32 + (ot - 2) * 16 + l15);
        u32x4 af = *(const u32x4*)(wkv + (size_t)row * 256 + kk * 32 + hi * 8);
        #pragma unroll
        for (int nt = 0; nt < 4; ++nt) acc[ot][nt] = mfma16(af, bfg[nt], acc[ot][nt]);
      }
    }

    const float scale = 0.17677669529663687f;   // 1/sqrt(32)
    #pragma unroll
    for (int hf = 0; hf < 2; ++hf){             // 32-m halves through per-wave LDS
      #pragma unroll
      for (int ot = 0; ot < 4; ++ot){
        #pragma unroll
        for (int ntl = 0; ntl < 2; ++ntl){
          int mcol = ntl * 16 + l15;
          #pragma unroll
          for (int r = 0; r < 4; ++r){
            float p = acc[ot][hf * 2 + ntl][r];
            // k = (elu(p)+1)*scale ; v = p
            float v0 = (ot < 2) ? ((p > 0.f ? p + 1.f : __expf(p)) * scale) : p;
            int rowk = ot * 16 + hi * 4 + r;    // 0..31 = k rows, 32..63 = v rows
            *(unsigned short*)((char*)kvw[w] + rowk * 64 + ((mcol * 2) ^ swz4(rowk))) = f2bf(v0);
          }
        }
      }
      // KV[c,d] += sum_m k[c,m] v[d,m] ; ksum[c] += sum_m k[c,m]
      #pragma unroll
      for (int ct = 0; ct < 2; ++ct){
        int ra = ct * 16 + l15;
        u32x4 afk = *(const u32x4*)((const char*)kvw[w] + ra * 64 + ((hi * 16) ^ swz4(ra)));
        #pragma unroll
        for (int dt = 0; dt < 2; ++dt){
          int rb = 32 + dt * 16 + l15;
          u32x4 bfv = *(const u32x4*)((const char*)kvw[w] + rb * 64 + ((hi * 16) ^ swz4(rb)));
          kvacc[ct][dt] = mfma16(afk, bfv, kvacc[ct][dt]);
        }
        ksacc[ct] = mfma16(afk, ones, ksacc[ct]);
      }
    }
  }

  // partial stores: kvp [b][16 ch][8 h][32 c][32 d], ksp [b][16 ch][8 h][32 c]
  size_t base = (((size_t)b * 16 + ch) * 8 + w) * 1024;
  #pragma unroll
  for (int ct = 0; ct < 2; ++ct){
    #pragma unroll
    for (int dt = 0; dt < 2; ++dt){
      #pragma unroll
      for (int r = 0; r < 4; ++r){
        int c = ct * 16 + hi * 4 + r, d = dt * 16 + l15;
        kvp[base + c * 32 + d] = kvacc[ct][dt][r];
      }
    }
  }
  if (l15 == 0){
    size_t kb = (((size_t)b * 16 + ch) * 8 + w) * 32;
    #pragma unroll
    for (int ct = 0; ct < 2; ++ct)
      #pragma unroll
      for (int r = 0; r < 4; ++r) ksp[kb + ct * 16 + hi * 4 + r] = ksacc[ct][r];
  }
}

// ---------------- kernel 2: reduce partials -> KV^T bf16 [b][h][d][c], ksum bf16
__global__ void k_red(const float* __restrict__ kvp, const float* __restrict__ ksp,
                      unsigned short* __restrict__ kvt, unsigned short* __restrict__ ksb){
  int t = blockIdx.x * 256 + threadIdx.x;   // (b,h,c)
  if (t >= 4096) return;
  int c = t & 31, h = (t >> 5) & 7, b = t >> 8;
  float kv[32];
  #pragma unroll
  for (int d = 0; d < 32; ++d) kv[d] = 0.f;
  float ks = 0.f;
  for (int c2 = 0; c2 < 16; ++c2){
    const float* p = kvp + ((((size_t)b * 16 + c2) * 8 + h) * 1024) + c * 32;
    #pragma unroll
    for (int d = 0; d < 32; ++d) kv[d] += p[d];
    ks += ksp[(((size_t)b * 16 + c2) * 8 + h) * 32 + c];
  }
  unsigned short* q = kvt + ((size_t)b * 8 + h) * 1024;
  #pragma unroll
  for (int d = 0; d < 32; ++d) q[d * 32 + c] = f2bf(kv[d]);   // transpose -> [d][c]
  ksb[((size_t)b * 8 + h) * 32 + c] = f2bf(ks);
}

// ---------------- kernel 3: Q projection + out = KV^T q / max(ksum.q, 1e-6) ----
// grid (64 m-tiles, 16 batches), 512 threads = 8 waves = 8 heads.
__global__ void __launch_bounds__(512) k_q(const float* __restrict__ x,
        const unsigned short* __restrict__ wqb,
        const unsigned short* __restrict__ kvt,
        const unsigned short* __restrict__ ksb,
        float* __restrict__ out){
  __shared__ unsigned short xT[16384];      // 32KB
  __shared__ unsigned short qld[8][2048];   // 32KB: per-wave q^T [64 m][32 c] bf16
  const int tid = threadIdx.x, lane = tid & 63, w = tid >> 6;
  const int l15 = lane & 15, hi = lane >> 4;
  const int mt = blockIdx.x, b = blockIdx.y;
  const int m0 = mt * 64;
  const float* xb = x + (size_t)b * (256 * 4096);

  stage_x(xb, m0, xT, tid);
  __syncthreads();

  f32x4 qa[2][4];
  #pragma unroll
  for (int a1 = 0; a1 < 2; ++a1)
    #pragma unroll
    for (int a2 = 0; a2 < 4; ++a2) qa[a1][a2] = f32x4{0.f,0.f,0.f,0.f};

  for (int kk = 0; kk < 8; ++kk){
    u32x4 bfg[4];
    #pragma unroll
    for (int nt = 0; nt < 4; ++nt){
      int m = nt * 16 + l15;
      bfg[nt] = *(const u32x4*)((const char*)xT + m * 512 + ((kk * 64 + hi * 16) ^ swz8(m)));
    }
    #pragma unroll
    for (int ot = 0; ot < 2; ++ot){
      int row = w * 32 + ot * 16 + l15;     // head w channels
      u32x4 af = *(const u32x4*)(wqb + (size_t)row * 256 + kk * 32 + hi * 8);
      #pragma unroll
      for (int nt = 0; nt < 4; ++nt) qa[ot][nt] = mfma16(af, bfg[nt], qa[ot][nt]);
    }
  }

  const float scale = 0.17677669529663687f;
  #pragma unroll
  for (int ot = 0; ot < 2; ++ot){
    #pragma unroll
    for (int nt = 0; nt < 4; ++nt){
      int m = nt * 16 + l15;
      unsigned short hb[4];
      #pragma unroll
      for (int r = 0; r < 4; ++r){
        float p = qa[ot][nt][r];
        hb[r] = f2bf((p > 0.f ? p + 1.f : __expf(p)) * scale);
      }
      unsigned long long v = (unsigned long long)((unsigned int)hb[0] | ((unsigned int)hb[1] << 16))
                           | ((unsigned long long)((unsigned int)hb[2] | ((unsigned int)hb[3] << 16)) << 32);
      int off = m * 64 + ((ot * 32 + hi * 8) ^ swz4(m));
      *(unsigned long long*)((char*)qld[w] + off) = v;
    }
  }
  // per-wave LDS only -> no barrier needed (in-wave lgkmcnt ordering)

  size_t kvbase = ((size_t)b * 8 + w) * 1024;
  u32x4 afkv0 = *(const u32x4*)(kvt + kvbase + (size_t)l15 * 32 + hi * 8);        // d = l15
  u32x4 afkv1 = *(const u32x4*)(kvt + kvbase + (size_t)(16 + l15) * 32 + hi * 8); // d = 16+l15
  u32x4 afd = {0u,0u,0u,0u};                 // row0 = ksum -> D[0][m] = denom
  if (l15 == 0) afd = *(const u32x4*)(ksb + ((size_t)b * 8 + w) * 32 + hi * 8);

  float* ob = out + ((size_t)b * 256 + w * 32) * 4096 + m0;
  #pragma unroll
  for (int nt = 0; nt < 4; ++nt){
    int m = nt * 16 + l15;
    u32x4 bq = *(const u32x4*)((const char*)qld[w] + m * 64 + ((hi * 16) ^ swz4(m)));
    f32x4 o0 = {0.f,0.f,0.f,0.f}, o1 = {0.f,0.f,0.f,0.f}, dn = {0.f,0.f,0.f,0.f};
    o0 = mfma16(afkv0, bq, o0);
    o1 = mfma16(afkv1, bq, o1);
    dn = mfma16(afd, bq, dn);
    float dv = __shfl(dn[0], l15, 64);       // lanes 0..15 hold denom[m] in reg0
    float inv = 1.0f / fmaxf(dv, 1e-6f);
    #pragma unroll
    for (int r = 0; r < 4; ++r){
      ob[(size_t)(hi * 4 + r) * 4096 + nt * 16 + l15]      = o0[r] * inv;
      ob[(size_t)(16 + hi * 4 + r) * 4096 + nt * 16 + l15] = o1[r] * inv;
    }
  }
}

extern "C" void kernel_launch(void* const* d_in, const int* in_sizes, int n_in,
                              void* d_out, int out_size, void* d_ws, size_t ws_size,
                              hipStream_t stream) {
  const float* x  = (const float*)d_in[0];
  const float* wq = (const float*)d_in[1];
  const float* wk = (const float*)d_in[2];
  const float* wv = (const float*)d_in[3];
  float* out = (float*)d_out;
  char* ws = (char*)d_ws;

  // ws layout (bytes): total ~9.25 MB
  unsigned short* wkv = (unsigned short*)(ws);                 // 512*256*2 = 262144
  unsigned short* wqb = (unsigned short*)(ws + 262144);        // 256*256*2 = 131072
  unsigned short* kvt = (unsigned short*)(ws + 393216);        // 16*8*32*32*2 = 262144
  unsigned short* ksb = (unsigned short*)(ws + 655360);        // 16*8*32*2 = 8192
  float* kvp = (float*)(ws + 1048576);                         // 16*16*8*1024*4 = 8388608
  float* ksp = (float*)(ws + 1048576 + 8388608);               // 16*16*8*32*4 = 262144

  hipLaunchKernelGGL(wconv, dim3(256), dim3(256), 0, stream, wq, wk, wv, wkv, wqb);
  hipLaunchKernelGGL(k_kv,  dim3(16, 16), dim3(512), 0, stream, x, wkv, kvp, ksp);
  hipLaunchKernelGGL(k_red, dim3(16), dim3(256), 0, stream, kvp, ksp, kvt, ksb);
  hipLaunchKernelGGL(k_q,   dim3(64, 16), dim3(512), 0, stream, x, wqb, kvt, ksb, out);
}